// Round 18
// baseline (135.230 us; speedup 1.0000x reference)
//
#include <hip/hip_runtime.h>

typedef unsigned long long u64;
typedef unsigned int u32;
typedef unsigned short u16;
typedef int i32x4 __attribute__((ext_vector_type(4)));
typedef int i32x16 __attribute__((ext_vector_type(16)));

#define HW 3136      // 56*56
#define XPITCH 3600  // padded 60*60 pixels per image
#define NPPIX 115200 // 32 * 3600 padded pixels
#define KTOT 2304    // 9 taps * 256 ci
#define MT 128       // pixels per conv block
#define NSTEP 36     // K steps of 64

// ============================ MFMA-i8 path ==================================
// Global layouts (chunk-planar so staging is coalesced AND LDS is linear):
//   xi8p: [ci_chunk 0..15][padded pixel 0..115199][16 B]   (29,491,200 B)
//   wi8p: [k_chunk 0..143][co 0..255][16 B]                (   589,824 B)

// ---- fused pack: blocks [0,1800) pack x, [1800,2376) pack W ----------------
__global__ __launch_bounds__(256) void pack_all(const float* __restrict__ x,
                                                const float* __restrict__ W,
                                                char* __restrict__ xp,
                                                char* __restrict__ wp,
                                                u64* __restrict__ ssum) {
    int bx = blockIdx.x;
    if (bx < 1800) {
        int word = bx / 450;                     // ci quarter (64 ch = 4 chunks)
        int s = (bx % 450) * 256 + threadIdx.x;  // padded pixel in [0, 115200)
        int n = s / XPITCH, p = s % XPITCH;
        int h = p / 60, w = p % 60;
        bool inb = (h >= 2 && h < 58 && w >= 2 && w < 58);
        u64 b = 0;
        if (inb) {
            const float* px = x + ((size_t)(n * 256 + word * 64)) * HW + (h - 2) * 56 + (w - 2);
            #pragma unroll 8
            for (int ci = 0; ci < 64; ++ci) {
                float v = px[(size_t)ci * HW];
                if (v >= 0.f) b |= 1ull << ci;
            }
        }
        #pragma unroll
        for (int q = 0; q < 4; ++q) {            // one 16B chunk per q
            u32 wds[4];
            #pragma unroll
            for (int j = 0; j < 4; ++j) {
                u32 bits = (u32)(b >> (q * 16 + j * 4)) & 15u;
                u32 t = (bits * 0x00204081u) & 0x01010101u;  // bit j -> byte j
                wds[j] = inb ? (~(t * 0xFEu)) : 0u;          // 1->0x01, 0->0xFF, pad->0
            }
            *(uint4*)(xp + (((long)(word * 4 + q)) * NPPIX + s) * 16) =
                make_uint4(wds[0], wds[1], wds[2], wds[3]);
        }
    } else {
        int bi = bx - 1800;
        if (bi == 0) {                           // zero stats accumulators
            ssum[threadIdx.x] = 0;
            ssum[threadIdx.x + 256] = 0;
        }
        int idx = bi * 256 + threadIdx.x;        // 147456 = 2304 * 64
        int ci4 = idx & 63;                      // ci0 = ci4*4
        int tapco = idx >> 6;
        int co = tapco / 9, tap = tapco % 9;
        u32 out = 0;
        #pragma unroll
        for (int k = 0; k < 4; ++k) {
            float v = W[((size_t)co * 256 + ci4 * 4 + k) * 9 + tap];
            out |= (v >= 0.f ? 0x01u : 0xFFu) << (8 * k);
        }
        int kc = tap * 16 + (ci4 >> 2);          // k-chunk
        *(u32*)(wp + ((long)kc * 256 + co) * 16 + (ci4 & 3) * 4) = out;
    }
}

// ---- i8 MFMA conv: R16 counted-vmcnt pipeline + T5 setprio -----------------
// LDS per buffer: X [4 chunks][128 rows][16B] = 8 KB | W [4][256][16B] = 16 KB.
// Steady state: vmcnt(3) keeps next stage's 3 loads in flight across the
// barrier (no vmcnt(0) drain per step). VGPR must stay <= 64 (cliff).
__global__ __launch_bounds__(512) void conv_mfma(const char* __restrict__ xp,
                                                 const char* __restrict__ wp,
                                                 short* __restrict__ y) {
    __shared__ char lds[2][24576];
    int tid = threadIdx.x;
    int lane = tid & 63, wid = tid >> 6;
    int wm = wid & 1, wn = wid >> 1;   // wave: px half (64), co quarter (64)
    long tile = blockIdx.x;

    // X staging: thread covers (local chunk = tid>>7, row = tid&127)
    int xrow = tid & 127, xlc = tid >> 7;
    long s0 = tile * MT + xrow;
    int xn = (int)(s0 / HW), xhw = (int)(s0 % HW);
    long xpix = (long)xn * XPITCH + (xhw / 56) * 60 + (xhw % 56);

    i32x16 acc00 = {}, acc01 = {}, acc10 = {}, acc11 = {};

#define STAGE(step, buf)                                                                  \
    {                                                                                     \
        int tap = (step) >> 2, q = (step) & 3;                                            \
        long shift = (long)((tap / 3) * 120 + (tap % 3) * 2);                             \
        long xaddr = (((long)(q * 4 + xlc)) * NPPIX + xpix + shift) * 16;                 \
        __builtin_amdgcn_global_load_lds(                                                 \
            (const __attribute__((address_space(1))) u32*)(xp + xaddr),                   \
            (__attribute__((address_space(3))) u32*)&lds[buf][wid * 1024], 16, 0, 0);     \
        _Pragma("unroll")                                                                 \
        for (int r = 0; r < 2; ++r) {                                                     \
            int L = r * 512 + tid;                                                        \
            long waddr = (((long)(tap * 16 + q * 4 + (L >> 8))) * 256 + (L & 255)) * 16;  \
            __builtin_amdgcn_global_load_lds(                                             \
                (const __attribute__((address_space(1))) u32*)(wp + waddr),               \
                (__attribute__((address_space(3))) u32*)&lds[buf][8192 + (r * 512 + wid * 64) * 16], \
                16, 0, 0);                                                                \
        }                                                                                 \
    }

#define COMPUTE(buf)                                                                      \
    {                                                                                     \
        __builtin_amdgcn_s_setprio(1);                                                    \
        _Pragma("unroll")                                                                 \
        for (int kc = 0; kc < 2; ++kc) {                                                  \
            int cx = kc * 2 + (lane >> 5);                                                \
            const char* xb = &lds[buf][cx * 2048 + (wm * 64 + (lane & 31)) * 16];         \
            const char* wb = &lds[buf][8192 + cx * 4096 + (wn * 64 + (lane & 31)) * 16];  \
            i32x4 xf0 = *(const i32x4*)xb;                                                \
            i32x4 xf1 = *(const i32x4*)(xb + 512);                                        \
            i32x4 wf0 = *(const i32x4*)wb;                                                \
            i32x4 wf1 = *(const i32x4*)(wb + 512);                                        \
            acc00 = __builtin_amdgcn_mfma_i32_32x32x32_i8(wf0, xf0, acc00, 0, 0, 0);      \
            acc01 = __builtin_amdgcn_mfma_i32_32x32x32_i8(wf0, xf1, acc01, 0, 0, 0);      \
            acc10 = __builtin_amdgcn_mfma_i32_32x32x32_i8(wf1, xf0, acc10, 0, 0, 0);      \
            acc11 = __builtin_amdgcn_mfma_i32_32x32x32_i8(wf1, xf1, acc11, 0, 0, 0);      \
        }                                                                                 \
        __builtin_amdgcn_s_setprio(0);                                                    \
    }

    STAGE(0, 0);
    STAGE(1, 1);
    #pragma unroll 2
    for (int st = 0; st < NSTEP - 1; ++st) {
        int cur = st & 1;
        asm volatile("s_waitcnt vmcnt(3)" ::: "memory");   // step st landed; st+1 in flight
        __builtin_amdgcn_s_barrier();
        COMPUTE(cur);
        asm volatile("s_waitcnt lgkmcnt(0)" ::: "memory"); // my ds_reads done before buf reuse
        __builtin_amdgcn_s_barrier();
        if (st + 2 < NSTEP) STAGE(st + 2, cur);
    }
    asm volatile("s_waitcnt vmcnt(0)" ::: "memory");
    __builtin_amdgcn_s_barrier();
    COMPUTE((NSTEP - 1) & 1);
#undef STAGE
#undef COMPUTE

    // store: C/D col = px (lane&31), row = co = (r&3)+8*(r>>2)+4*(lane>>5)
    #pragma unroll
    for (int jp = 0; jp < 2; ++jp) {
        long s = tile * MT + wm * 64 + jp * 32 + (lane & 31);
        int n = (int)(s / HW), hw = (int)(s % HW);
        short* yb = y + ((long)n * 256) * HW + hw;
        #pragma unroll
        for (int jc = 0; jc < 2; ++jc) {
            i32x16 A = jc ? (jp ? acc11 : acc10) : (jp ? acc01 : acc00);
            #pragma unroll
            for (int r = 0; r < 16; ++r) {
                int co = wn * 64 + jc * 32 + (r & 3) + 8 * (r >> 2) + 4 * (lane >> 5);
                yb[(long)co * HW] = (short)A[r];
            }
        }
    }
}

// ============================ epilogue ======================================

__global__ __launch_bounds__(256) void stats1_kernel(const short* __restrict__ y,
                                                     u64* __restrict__ ssum) {
    int pl = blockIdx.x;                      // n*256 + c
    const short* p = y + (size_t)pl * HW;
    int tid = threadIdx.x;
    int a1 = 0; long long q1 = 0;
    for (int i = tid; i < 392; i += 256) {    // 392 short8 per plane
        int4 v = *(const int4*)(p + i * 8);
        int vs[4] = {v.x, v.y, v.z, v.w};
        int a = 0, q = 0;
        #pragma unroll
        for (int j = 0; j < 4; ++j) {
            int lo = (short)(vs[j] & 0xffff);
            int hi = (short)(vs[j] >> 16);
            a += lo + hi;
            q += lo * lo + hi * hi;
        }
        a1 += a; q1 += q;
    }
    long long s1 = a1, s2 = q1;
    #pragma unroll
    for (int off = 32; off > 0; off >>= 1) {
        s1 += __shfl_down(s1, off);
        s2 += __shfl_down(s2, off);
    }
    __shared__ long long ls1[4], ls2[4];
    if ((tid & 63) == 0) { ls1[tid >> 6] = s1; ls2[tid >> 6] = s2; }
    __syncthreads();
    if (tid == 0) {
        long long S1 = ls1[0] + ls1[1] + ls1[2] + ls1[3];
        long long S2 = ls2[0] + ls2[1] + ls2[2] + ls2[3];
        int cch = pl & 255;
        atomicAdd(&ssum[cch],       (u64)S1);
        atomicAdd(&ssum[256 + cch], (u64)S2);
    }
}

__global__ __launch_bounds__(256) void norm_kernel(const short* __restrict__ y,
                                                   const u64* __restrict__ ssum,
                                                   const float* __restrict__ gamma,
                                                   const float* __restrict__ beta,
                                                   float* __restrict__ out) {
    size_t i = ((size_t)blockIdx.x * 256 + threadIdx.x) * 8;
    int cch = (int)((i / HW) & 255);
    double S1 = (double)(long long)ssum[cch];
    double S2 = (double)(long long)ssum[256 + cch];
    double mean = S1 / 100352.0;
    double var = S2 / 100352.0 - mean * mean;
    float a = gamma[cch] * rsqrtf((float)var + 1e-5f);
    float b = beta[cch] - (float)mean * a;

    int4 v = *(const int4*)(y + i);
    int vs[4] = {v.x, v.y, v.z, v.w};
    float r[8];
    #pragma unroll
    for (int j = 0; j < 4; ++j) {
        short lo = (short)(vs[j] & 0xffff);
        short hi = (short)(vs[j] >> 16);
        r[2 * j]     = tanhf(a * (float)lo + b);
        r[2 * j + 1] = tanhf(a * (float)hi + b);
    }
    *(float4*)(out + i)     = make_float4(r[0], r[1], r[2], r[3]);
    *(float4*)(out + i + 4) = make_float4(r[4], r[5], r[6], r[7]);
}

// ===================== fallback (R8 popcount path) ==========================

__global__ __launch_bounds__(256) void pack_w_kernel(const float* __restrict__ W,
                                                     u32* __restrict__ wp32,
                                                     u16* __restrict__ pw,
                                                     u64* __restrict__ ssum) {
    if (blockIdx.x == 0) {
        ssum[threadIdx.x] = 0;
        ssum[threadIdx.x + 256] = 0;
    }
    int t = blockIdx.x * 256 + threadIdx.x;
    int co = t / 9, tap = t % 9;
    u64 b[4] = {0, 0, 0, 0};
    for (int ci = 0; ci < 256; ++ci) {
        float v = W[(size_t)(co * 256 + ci) * 9 + tap];
        if (v >= 0.f) b[ci >> 6] |= 1ull << (ci & 63);
    }
    u32* dst = wp32 + ((size_t)tap * 256 + co) * 8;
    #pragma unroll
    for (int j = 0; j < 4; ++j) {
        dst[2 * j]     = (u32)b[j];
        dst[2 * j + 1] = (u32)(b[j] >> 32);
    }
    pw[co * 9 + tap] = (u16)(__popcll(b[0]) + __popcll(b[1]) + __popcll(b[2]) + __popcll(b[3]));
}

__global__ __launch_bounds__(256) void pack_x_kernel(const float* __restrict__ x,
                                                     u64* __restrict__ xpad,
                                                     const u16* __restrict__ pw,
                                                     u16* __restrict__ bias) {
    int s = blockIdx.x * 256 + threadIdx.x;
    int word = blockIdx.y;
    int n = s / XPITCH, p = s % XPITCH;
    int h = p / 60, w = p % 60;
    u64 b = 0;
    if (h >= 2 && h < 58 && w >= 2 && w < 58) {
        const float* px = x + ((size_t)(n * 256 + word * 64)) * HW + (h - 2) * 56 + (w - 2);
        #pragma unroll 8
        for (int ci = 0; ci < 64; ++ci) {
            float v = px[(size_t)ci * HW];
            if (v >= 0.f) b |= 1ull << ci;
        }
    }
    xpad[(size_t)s * 4 + word] = b;

    if (blockIdx.x == 0 && blockIdx.y == 0) {
        for (int i = threadIdx.x; i < 9 * 256; i += 256) {
            int mi = i >> 8, co = i & 255;
            int rm = mi / 3, cm = mi % 3;
            int vr = rm == 0 ? 6 : (rm == 2 ? 3 : 7);
            int vc = cm == 0 ? 6 : (cm == 2 ? 3 : 7);
            int corr = 0;
            for (int kh = 0; kh < 3; ++kh)
                for (int kw = 0; kw < 3; ++kw)
                    if (!(((vr >> kh) & 1) && ((vc >> kw) & 1)))
                        corr += pw[co * 9 + kh * 3 + kw];
            bias[mi * 256 + co] = (u16)(256 * __popc(vr) * __popc(vc) + 2 * corr);
        }
    }
}

#define CPT 8
__global__ __launch_bounds__(256) void conv_kernel(const u32* __restrict__ xpad,
                                                   const u32* __restrict__ wp32,
                                                   const u16* __restrict__ bias,
                                                   short* __restrict__ y) {
    int s = blockIdx.x * 256 + threadIdx.x;
    int n = s / HW, hw = s % HW;
    int h = hw / 56, w = hw % 56;
    int co0 = blockIdx.y * CPT;
    const u32* xb = xpad + ((size_t)n * XPITCH + h * 60 + w) * 8;
    uint4 xa[9], xc[9];
    #pragma unroll
    for (int kh = 0; kh < 3; ++kh)
        #pragma unroll
        for (int kw = 0; kw < 3; ++kw) {
            const u32* px = xb + (kh * 120 + kw * 2) * 8;
            xa[kh * 3 + kw] = *(const uint4*)(px);
            xc[kh * 3 + kw] = *(const uint4*)(px + 4);
        }
    int acc[CPT];
    #pragma unroll
    for (int cc = 0; cc < CPT; ++cc) acc[cc] = 0;
    #pragma unroll
    for (int t = 0; t < 9; ++t) {
        const u32* wt = wp32 + (((size_t)t * 256 + co0) * 8);
        uint4 a = xa[t], b = xc[t];
        #pragma unroll
        for (int cc = 0; cc < CPT; ++cc) {
            const u32* wc8 = wt + cc * 8;
            acc[cc] = __popc(a.x ^ wc8[0]) + acc[cc];
            acc[cc] = __popc(a.y ^ wc8[1]) + acc[cc];
            acc[cc] = __popc(a.z ^ wc8[2]) + acc[cc];
            acc[cc] = __popc(a.w ^ wc8[3]) + acc[cc];
            acc[cc] = __popc(b.x ^ wc8[4]) + acc[cc];
            acc[cc] = __popc(b.y ^ wc8[5]) + acc[cc];
            acc[cc] = __popc(b.z ^ wc8[6]) + acc[cc];
            acc[cc] = __popc(b.w ^ wc8[7]) + acc[cc];
        }
    }
    int rm = (h < 2) ? 0 : (h > 53 ? 2 : 1);
    int cm = (w < 2) ? 0 : (w > 53 ? 2 : 1);
    int mi = rm * 3 + cm;
    uint4 bv = *(const uint4*)(bias + (size_t)mi * 256 + co0);
    u32 bw[4] = {bv.x, bv.y, bv.z, bv.w};
    short* yo = y + ((size_t)n * 256 + co0) * HW + hw;
    #pragma unroll
    for (int cc = 0; cc < CPT; ++cc) {
        int bval = (int)((bw[cc >> 1] >> ((cc & 1) * 16)) & 0xffff);
        yo[(size_t)cc * HW] = (short)(bval - 2 * acc[cc]);
    }
}

// ================================ launch ====================================

extern "C" void kernel_launch(void* const* d_in, const int* in_sizes, int n_in,
                              void* d_out, int out_size, void* d_ws, size_t ws_size,
                              hipStream_t stream) {
    const float* x     = (const float*)d_in[0];
    const float* W     = (const float*)d_in[1];
    const float* gamma = (const float*)d_in[2];
    const float* beta  = (const float*)d_in[3];
    float* out = (float*)d_out;
    char* ws = (char*)d_ws;

    short* y = (short*)ws;                             // 51,380,224 B

    if (ws_size >= 81465344) {
        // MFMA path: 4 dispatches
        char* xi8 = ws + 51380224;                     // 29,491,200 B (chunk-planar)
        char* wi8 = ws + 80871424;                     //    589,824 B (chunk-planar)
        u64* ssum = (u64*)(ws + 81461248);             //      4,096 B
        pack_all<<<2376, 256, 0, stream>>>(x, W, xi8, wi8, ssum);
        conv_mfma<<<784, 512, 0, stream>>>(xi8, wi8, y);
        stats1_kernel<<<8192, 256, 0, stream>>>(y, ssum);
        norm_kernel<<<12544, 256, 0, stream>>>(y, ssum, gamma, beta, out);
    } else {
        // popcount fallback (R8)
        u64* xpad = (u64*)(ws + 51380224);
        u32* wp32 = (u32*)(ws + 55066624);
        u16* pw   = (u16*)(ws + 55140352);
        u16* bias = (u16*)(ws + 55144960);
        u64* ssum = (u64*)(ws + 55149568);
        pack_w_kernel<<<9, 256, 0, stream>>>(W, wp32, pw, ssum);
        pack_x_kernel<<<dim3(450, 4), 256, 0, stream>>>(x, xpad, pw, bias);
        conv_kernel<<<dim3(392, 32), 256, 0, stream>>>((const u32*)xpad, wp32, bias, y);
        stats1_kernel<<<8192, 256, 0, stream>>>(y, ssum);
        norm_kernel<<<12544, 256, 0, stream>>>(y, ssum, gamma, beta, out);
    }
}

// Round 19
// 131.164 us; speedup vs baseline: 1.0310x; 1.0310x over previous
//
#include <hip/hip_runtime.h>

typedef unsigned long long u64;
typedef unsigned int u32;
typedef unsigned short u16;
typedef int i32x4 __attribute__((ext_vector_type(4)));
typedef int i32x16 __attribute__((ext_vector_type(16)));

#define HW 3136      // 56*56
#define XPITCH 3600  // padded 60*60 pixels per image
#define NPPIX 115200 // 32 * 3600 padded pixels
#define KTOT 2304    // 9 taps * 256 ci
#define MT 128       // pixels per conv block
#define NSTEP 36     // K steps of 64

// ============================ MFMA-i8 path ==================================
// Global layouts (chunk-planar so staging is coalesced AND LDS is linear):
//   xi8p: [ci_chunk 0..15][padded pixel 0..115199][16 B]   (29,491,200 B)
//   wi8p: [k_chunk 0..143][co 0..255][16 B]                (   589,824 B)

// ---- fused pack: blocks [0,1800) pack x, [1800,2376) pack W ----------------
__global__ __launch_bounds__(256) void pack_all(const float* __restrict__ x,
                                                const float* __restrict__ W,
                                                char* __restrict__ xp,
                                                char* __restrict__ wp,
                                                u64* __restrict__ ssum) {
    int bx = blockIdx.x;
    if (bx < 1800) {
        int word = bx / 450;                     // ci quarter (64 ch = 4 chunks)
        int s = (bx % 450) * 256 + threadIdx.x;  // padded pixel in [0, 115200)
        int n = s / XPITCH, p = s % XPITCH;
        int h = p / 60, w = p % 60;
        bool inb = (h >= 2 && h < 58 && w >= 2 && w < 58);
        u64 b = 0;
        if (inb) {
            const float* px = x + ((size_t)(n * 256 + word * 64)) * HW + (h - 2) * 56 + (w - 2);
            #pragma unroll 8
            for (int ci = 0; ci < 64; ++ci) {
                float v = px[(size_t)ci * HW];
                if (v >= 0.f) b |= 1ull << ci;
            }
        }
        #pragma unroll
        for (int q = 0; q < 4; ++q) {            // one 16B chunk per q
            u32 wds[4];
            #pragma unroll
            for (int j = 0; j < 4; ++j) {
                u32 bits = (u32)(b >> (q * 16 + j * 4)) & 15u;
                u32 t = (bits * 0x00204081u) & 0x01010101u;  // bit j -> byte j
                wds[j] = inb ? (~(t * 0xFEu)) : 0u;          // 1->0x01, 0->0xFF, pad->0
            }
            *(uint4*)(xp + (((long)(word * 4 + q)) * NPPIX + s) * 16) =
                make_uint4(wds[0], wds[1], wds[2], wds[3]);
        }
    } else {
        int bi = bx - 1800;
        if (bi == 0) {                           // zero stats accumulators
            ssum[threadIdx.x] = 0;
            ssum[threadIdx.x + 256] = 0;
        }
        int idx = bi * 256 + threadIdx.x;        // 147456 = 2304 * 64
        int ci4 = idx & 63;                      // ci0 = ci4*4
        int tapco = idx >> 6;
        int co = tapco / 9, tap = tapco % 9;
        u32 out = 0;
        #pragma unroll
        for (int k = 0; k < 4; ++k) {
            float v = W[((size_t)co * 256 + ci4 * 4 + k) * 9 + tap];
            out |= (v >= 0.f ? 0x01u : 0xFFu) << (8 * k);
        }
        int kc = tap * 16 + (ci4 >> 2);          // k-chunk
        *(u32*)(wp + ((long)kc * 256 + co) * 16 + (ci4 & 3) * 4) = out;
    }
}

// ---- i8 MFMA conv: counted-vmcnt pipeline (R16, best measured) -------------
// LDS per buffer: X [4 chunks][128 rows][16B] = 8 KB | W [4][256][16B] = 16 KB.
// Steady state: vmcnt(3) keeps next stage's 3 loads in flight across the
// barrier (no vmcnt(0) drain per step). VGPR must stay <= 64 (cliff).
// NO setprio (R18: -10%), NO sched_barrier (R12), NO 3-buf (R17: LDS cliff).
__global__ __launch_bounds__(512) void conv_mfma(const char* __restrict__ xp,
                                                 const char* __restrict__ wp,
                                                 short* __restrict__ y) {
    __shared__ char lds[2][24576];
    int tid = threadIdx.x;
    int lane = tid & 63, wid = tid >> 6;
    int wm = wid & 1, wn = wid >> 1;   // wave: px half (64), co quarter (64)
    long tile = blockIdx.x;

    // X staging: thread covers (local chunk = tid>>7, row = tid&127)
    int xrow = tid & 127, xlc = tid >> 7;
    long s0 = tile * MT + xrow;
    int xn = (int)(s0 / HW), xhw = (int)(s0 % HW);
    long xpix = (long)xn * XPITCH + (xhw / 56) * 60 + (xhw % 56);

    i32x16 acc00 = {}, acc01 = {}, acc10 = {}, acc11 = {};

#define STAGE(step, buf)                                                                  \
    {                                                                                     \
        int tap = (step) >> 2, q = (step) & 3;                                            \
        long shift = (long)((tap / 3) * 120 + (tap % 3) * 2);                             \
        long xaddr = (((long)(q * 4 + xlc)) * NPPIX + xpix + shift) * 16;                 \
        __builtin_amdgcn_global_load_lds(                                                 \
            (const __attribute__((address_space(1))) u32*)(xp + xaddr),                   \
            (__attribute__((address_space(3))) u32*)&lds[buf][wid * 1024], 16, 0, 0);     \
        _Pragma("unroll")                                                                 \
        for (int r = 0; r < 2; ++r) {                                                     \
            int L = r * 512 + tid;                                                        \
            long waddr = (((long)(tap * 16 + q * 4 + (L >> 8))) * 256 + (L & 255)) * 16;  \
            __builtin_amdgcn_global_load_lds(                                             \
                (const __attribute__((address_space(1))) u32*)(wp + waddr),               \
                (__attribute__((address_space(3))) u32*)&lds[buf][8192 + (r * 512 + wid * 64) * 16], \
                16, 0, 0);                                                                \
        }                                                                                 \
    }

#define COMPUTE(buf)                                                                      \
    {                                                                                     \
        _Pragma("unroll")                                                                 \
        for (int kc = 0; kc < 2; ++kc) {                                                  \
            int cx = kc * 2 + (lane >> 5);                                                \
            const char* xb = &lds[buf][cx * 2048 + (wm * 64 + (lane & 31)) * 16];         \
            const char* wb = &lds[buf][8192 + cx * 4096 + (wn * 64 + (lane & 31)) * 16];  \
            i32x4 xf0 = *(const i32x4*)xb;                                                \
            i32x4 xf1 = *(const i32x4*)(xb + 512);                                        \
            i32x4 wf0 = *(const i32x4*)wb;                                                \
            i32x4 wf1 = *(const i32x4*)(wb + 512);                                        \
            acc00 = __builtin_amdgcn_mfma_i32_32x32x32_i8(wf0, xf0, acc00, 0, 0, 0);      \
            acc01 = __builtin_amdgcn_mfma_i32_32x32x32_i8(wf0, xf1, acc01, 0, 0, 0);      \
            acc10 = __builtin_amdgcn_mfma_i32_32x32x32_i8(wf1, xf0, acc10, 0, 0, 0);      \
            acc11 = __builtin_amdgcn_mfma_i32_32x32x32_i8(wf1, xf1, acc11, 0, 0, 0);      \
        }                                                                                 \
    }

    STAGE(0, 0);
    STAGE(1, 1);
    #pragma unroll 2
    for (int st = 0; st < NSTEP - 1; ++st) {
        int cur = st & 1;
        asm volatile("s_waitcnt vmcnt(3)" ::: "memory");   // step st landed; st+1 in flight
        __builtin_amdgcn_s_barrier();
        COMPUTE(cur);
        asm volatile("s_waitcnt lgkmcnt(0)" ::: "memory"); // my ds_reads done before buf reuse
        __builtin_amdgcn_s_barrier();
        if (st + 2 < NSTEP) STAGE(st + 2, cur);
    }
    asm volatile("s_waitcnt vmcnt(0)" ::: "memory");
    __builtin_amdgcn_s_barrier();
    COMPUTE((NSTEP - 1) & 1);
#undef STAGE
#undef COMPUTE

    // store: C/D col = px (lane&31), row = co = (r&3)+8*(r>>2)+4*(lane>>5)
    #pragma unroll
    for (int jp = 0; jp < 2; ++jp) {
        long s = tile * MT + wm * 64 + jp * 32 + (lane & 31);
        int n = (int)(s / HW), hw = (int)(s % HW);
        short* yb = y + ((long)n * 256) * HW + hw;
        #pragma unroll
        for (int jc = 0; jc < 2; ++jc) {
            i32x16 A = jc ? (jp ? acc11 : acc10) : (jp ? acc01 : acc00);
            #pragma unroll
            for (int r = 0; r < 16; ++r) {
                int co = wn * 64 + jc * 32 + (r & 3) + 8 * (r >> 2) + 4 * (lane >> 5);
                yb[(long)co * HW] = (short)A[r];
            }
        }
    }
}

// ============================ epilogue ======================================

__global__ __launch_bounds__(256) void stats1_kernel(const short* __restrict__ y,
                                                     u64* __restrict__ ssum) {
    int pl = blockIdx.x;                      // n*256 + c
    const short* p = y + (size_t)pl * HW;
    int tid = threadIdx.x;
    int a1 = 0; long long q1 = 0;
    for (int i = tid; i < 392; i += 256) {    // 392 short8 per plane
        int4 v = *(const int4*)(p + i * 8);
        int vs[4] = {v.x, v.y, v.z, v.w};
        int a = 0, q = 0;
        #pragma unroll
        for (int j = 0; j < 4; ++j) {
            int lo = (short)(vs[j] & 0xffff);
            int hi = (short)(vs[j] >> 16);
            a += lo + hi;
            q += lo * lo + hi * hi;
        }
        a1 += a; q1 += q;
    }
    long long s1 = a1, s2 = q1;
    #pragma unroll
    for (int off = 32; off > 0; off >>= 1) {
        s1 += __shfl_down(s1, off);
        s2 += __shfl_down(s2, off);
    }
    __shared__ long long ls1[4], ls2[4];
    if ((tid & 63) == 0) { ls1[tid >> 6] = s1; ls2[tid >> 6] = s2; }
    __syncthreads();
    if (tid == 0) {
        long long S1 = ls1[0] + ls1[1] + ls1[2] + ls1[3];
        long long S2 = ls2[0] + ls2[1] + ls2[2] + ls2[3];
        int cch = pl & 255;
        atomicAdd(&ssum[cch],       (u64)S1);
        atomicAdd(&ssum[256 + cch], (u64)S2);
    }
}

__global__ __launch_bounds__(256) void norm_kernel(const short* __restrict__ y,
                                                   const u64* __restrict__ ssum,
                                                   const float* __restrict__ gamma,
                                                   const float* __restrict__ beta,
                                                   float* __restrict__ out) {
    size_t i = ((size_t)blockIdx.x * 256 + threadIdx.x) * 8;
    int cch = (int)((i / HW) & 255);
    double S1 = (double)(long long)ssum[cch];
    double S2 = (double)(long long)ssum[256 + cch];
    double mean = S1 / 100352.0;
    double var = S2 / 100352.0 - mean * mean;
    float a = gamma[cch] * rsqrtf((float)var + 1e-5f);
    float b = beta[cch] - (float)mean * a;

    int4 v = *(const int4*)(y + i);
    int vs[4] = {v.x, v.y, v.z, v.w};
    float r[8];
    #pragma unroll
    for (int j = 0; j < 4; ++j) {
        short lo = (short)(vs[j] & 0xffff);
        short hi = (short)(vs[j] >> 16);
        r[2 * j]     = tanhf(a * (float)lo + b);
        r[2 * j + 1] = tanhf(a * (float)hi + b);
    }
    *(float4*)(out + i)     = make_float4(r[0], r[1], r[2], r[3]);
    *(float4*)(out + i + 4) = make_float4(r[4], r[5], r[6], r[7]);
}

// ===================== fallback (R8 popcount path) ==========================

__global__ __launch_bounds__(256) void pack_w_kernel(const float* __restrict__ W,
                                                     u32* __restrict__ wp32,
                                                     u16* __restrict__ pw,
                                                     u64* __restrict__ ssum) {
    if (blockIdx.x == 0) {
        ssum[threadIdx.x] = 0;
        ssum[threadIdx.x + 256] = 0;
    }
    int t = blockIdx.x * 256 + threadIdx.x;
    int co = t / 9, tap = t % 9;
    u64 b[4] = {0, 0, 0, 0};
    for (int ci = 0; ci < 256; ++ci) {
        float v = W[(size_t)(co * 256 + ci) * 9 + tap];
        if (v >= 0.f) b[ci >> 6] |= 1ull << (ci & 63);
    }
    u32* dst = wp32 + ((size_t)tap * 256 + co) * 8;
    #pragma unroll
    for (int j = 0; j < 4; ++j) {
        dst[2 * j]     = (u32)b[j];
        dst[2 * j + 1] = (u32)(b[j] >> 32);
    }
    pw[co * 9 + tap] = (u16)(__popcll(b[0]) + __popcll(b[1]) + __popcll(b[2]) + __popcll(b[3]));
}

__global__ __launch_bounds__(256) void pack_x_kernel(const float* __restrict__ x,
                                                     u64* __restrict__ xpad,
                                                     const u16* __restrict__ pw,
                                                     u16* __restrict__ bias) {
    int s = blockIdx.x * 256 + threadIdx.x;
    int word = blockIdx.y;
    int n = s / XPITCH, p = s % XPITCH;
    int h = p / 60, w = p % 60;
    u64 b = 0;
    if (h >= 2 && h < 58 && w >= 2 && w < 58) {
        const float* px = x + ((size_t)(n * 256 + word * 64)) * HW + (h - 2) * 56 + (w - 2);
        #pragma unroll 8
        for (int ci = 0; ci < 64; ++ci) {
            float v = px[(size_t)ci * HW];
            if (v >= 0.f) b |= 1ull << ci;
        }
    }
    xpad[(size_t)s * 4 + word] = b;

    if (blockIdx.x == 0 && blockIdx.y == 0) {
        for (int i = threadIdx.x; i < 9 * 256; i += 256) {
            int mi = i >> 8, co = i & 255;
            int rm = mi / 3, cm = mi % 3;
            int vr = rm == 0 ? 6 : (rm == 2 ? 3 : 7);
            int vc = cm == 0 ? 6 : (cm == 2 ? 3 : 7);
            int corr = 0;
            for (int kh = 0; kh < 3; ++kh)
                for (int kw = 0; kw < 3; ++kw)
                    if (!(((vr >> kh) & 1) && ((vc >> kw) & 1)))
                        corr += pw[co * 9 + kh * 3 + kw];
            bias[mi * 256 + co] = (u16)(256 * __popc(vr) * __popc(vc) + 2 * corr);
        }
    }
}

#define CPT 8
__global__ __launch_bounds__(256) void conv_kernel(const u32* __restrict__ xpad,
                                                   const u32* __restrict__ wp32,
                                                   const u16* __restrict__ bias,
                                                   short* __restrict__ y) {
    int s = blockIdx.x * 256 + threadIdx.x;
    int n = s / HW, hw = s % HW;
    int h = hw / 56, w = hw % 56;
    int co0 = blockIdx.y * CPT;
    const u32* xb = xpad + ((size_t)n * XPITCH + h * 60 + w) * 8;
    uint4 xa[9], xc[9];
    #pragma unroll
    for (int kh = 0; kh < 3; ++kh)
        #pragma unroll
        for (int kw = 0; kw < 3; ++kw) {
            const u32* px = xb + (kh * 120 + kw * 2) * 8;
            xa[kh * 3 + kw] = *(const uint4*)(px);
            xc[kh * 3 + kw] = *(const uint4*)(px + 4);
        }
    int acc[CPT];
    #pragma unroll
    for (int cc = 0; cc < CPT; ++cc) acc[cc] = 0;
    #pragma unroll
    for (int t = 0; t < 9; ++t) {
        const u32* wt = wp32 + (((size_t)t * 256 + co0) * 8);
        uint4 a = xa[t], b = xc[t];
        #pragma unroll
        for (int cc = 0; cc < CPT; ++cc) {
            const u32* wc8 = wt + cc * 8;
            acc[cc] = __popc(a.x ^ wc8[0]) + acc[cc];
            acc[cc] = __popc(a.y ^ wc8[1]) + acc[cc];
            acc[cc] = __popc(a.z ^ wc8[2]) + acc[cc];
            acc[cc] = __popc(a.w ^ wc8[3]) + acc[cc];
            acc[cc] = __popc(b.x ^ wc8[4]) + acc[cc];
            acc[cc] = __popc(b.y ^ wc8[5]) + acc[cc];
            acc[cc] = __popc(b.z ^ wc8[6]) + acc[cc];
            acc[cc] = __popc(b.w ^ wc8[7]) + acc[cc];
        }
    }
    int rm = (h < 2) ? 0 : (h > 53 ? 2 : 1);
    int cm = (w < 2) ? 0 : (w > 53 ? 2 : 1);
    int mi = rm * 3 + cm;
    uint4 bv = *(const uint4*)(bias + (size_t)mi * 256 + co0);
    u32 bw[4] = {bv.x, bv.y, bv.z, bv.w};
    short* yo = y + ((size_t)n * 256 + co0) * HW + hw;
    #pragma unroll
    for (int cc = 0; cc < CPT; ++cc) {
        int bval = (int)((bw[cc >> 1] >> ((cc & 1) * 16)) & 0xffff);
        yo[(size_t)cc * HW] = (short)(bval - 2 * acc[cc]);
    }
}

// ================================ launch ====================================

extern "C" void kernel_launch(void* const* d_in, const int* in_sizes, int n_in,
                              void* d_out, int out_size, void* d_ws, size_t ws_size,
                              hipStream_t stream) {
    const float* x     = (const float*)d_in[0];
    const float* W     = (const float*)d_in[1];
    const float* gamma = (const float*)d_in[2];
    const float* beta  = (const float*)d_in[3];
    float* out = (float*)d_out;
    char* ws = (char*)d_ws;

    short* y = (short*)ws;                             // 51,380,224 B

    if (ws_size >= 81465344) {
        // MFMA path: 4 dispatches
        char* xi8 = ws + 51380224;                     // 29,491,200 B (chunk-planar)
        char* wi8 = ws + 80871424;                     //    589,824 B (chunk-planar)
        u64* ssum = (u64*)(ws + 81461248);             //      4,096 B
        pack_all<<<2376, 256, 0, stream>>>(x, W, xi8, wi8, ssum);
        conv_mfma<<<784, 512, 0, stream>>>(xi8, wi8, y);
        stats1_kernel<<<8192, 256, 0, stream>>>(y, ssum);
        norm_kernel<<<12544, 256, 0, stream>>>(y, ssum, gamma, beta, out);
    } else {
        // popcount fallback (R8)
        u64* xpad = (u64*)(ws + 51380224);
        u32* wp32 = (u32*)(ws + 55066624);
        u16* pw   = (u16*)(ws + 55140352);
        u16* bias = (u16*)(ws + 55144960);
        u64* ssum = (u64*)(ws + 55149568);
        pack_w_kernel<<<9, 256, 0, stream>>>(W, wp32, pw, ssum);
        pack_x_kernel<<<dim3(450, 4), 256, 0, stream>>>(x, xpad, pw, bias);
        conv_kernel<<<dim3(392, 32), 256, 0, stream>>>((const u32*)xpad, wp32, bias, y);
        stats1_kernel<<<8192, 256, 0, stream>>>(y, ssum);
        norm_kernel<<<12544, 256, 0, stream>>>(y, ssum, gamma, beta, out);
    }
}